// Round 12
// baseline (198.045 us; speedup 1.0000x reference)
//
#include <hip/hip_runtime.h>
#include <hip/hip_bf16.h>
#include <stdint.h>

#define T_SEQ 2048
#define EMB   512
#define NH    8
#define HEAD_ALL 4096   // NH*EMB

typedef __attribute__((ext_vector_type(8))) short short8;
typedef __attribute__((ext_vector_type(4))) float f32x4;

__device__ __forceinline__ unsigned short f2b(float f) {
    __hip_bfloat16 h = __float2bfloat16(f);
    return *reinterpret_cast<unsigned short*>(&h);
}
__device__ __forceinline__ float b2f(unsigned short u) {
    return __uint_as_float(((unsigned)u) << 16);
}
__device__ __forceinline__ void gload_lds16(const void* g, void* l) {
    __builtin_amdgcn_global_load_lds((__attribute__((address_space(1))) void*)(void*)(g),
                                     (__attribute__((address_space(3))) void*)(l), 16, 0, 0);
}
__device__ __forceinline__ void wg_barrier() {
    asm volatile("" ::: "memory");
    __builtin_amdgcn_s_barrier();
    asm volatile("" ::: "memory");
}

// ---------------- f32 -> bf16 convert, two tensors in one launch ----------------
__global__ void cvt_bf16_2(const float* __restrict__ a, const float* __restrict__ b,
                           unsigned short* __restrict__ oa, unsigned short* __restrict__ ob, int n8) {
    const float* in = blockIdx.y ? b : a;
    unsigned short* out = blockIdx.y ? ob : oa;
    int i = blockIdx.x * 256 + threadIdx.x;
    if (i >= n8) return;
    const f32x4* p = (const f32x4*)in + 2 * (size_t)i;
    f32x4 va = p[0], vb = p[1];
    uint4 o;
    o.x = (unsigned)f2b(va[0]) | ((unsigned)f2b(va[1]) << 16);
    o.y = (unsigned)f2b(va[2]) | ((unsigned)f2b(va[3]) << 16);
    o.z = (unsigned)f2b(vb[0]) | ((unsigned)f2b(vb[1]) << 16);
    o.w = (unsigned)f2b(vb[2]) | ((unsigned)f2b(vb[3]) << 16);
    *((uint4*)out + i) = o;
}

// ------- f32 [R][C] -> bf16 [C][R] transpose-convert, z selects source -------
__global__ void transpose_cvt3_f32(const float* __restrict__ w0, const float* __restrict__ w1,
                                   const float* __restrict__ w2, unsigned short* __restrict__ out,
                                   int R, int C, long outS) {
    __shared__ unsigned short t[64][66];
    const int z = blockIdx.z;
    const float* in = (z == 0) ? w0 : ((z == 1) ? w1 : w2);
    unsigned short* ob = out + (long)z * outS;
    const int tid = threadIdx.x;
    const int r0 = blockIdx.y * 64, c0 = blockIdx.x * 64;
#pragma unroll
    for (int it = 0; it < 4; ++it) {
        int flat = it * 256 + tid;
        int r = flat >> 4, c4 = flat & 15;
        f32x4 v = *(const f32x4*)(in + (long)(r0 + r) * C + c0 + c4 * 4);
#pragma unroll
        for (int w = 0; w < 4; ++w) t[r][c4 * 4 + w] = f2b(v[w]);
    }
    __syncthreads();
#pragma unroll
    for (int it = 0; it < 2; ++it) {
        int flat = it * 256 + tid;
        int rr = flat >> 3, c8 = flat & 7;
        unsigned u[4];
#pragma unroll
        for (int w = 0; w < 4; ++w) {
            unsigned short a = t[c8 * 8 + 2 * w][rr];
            unsigned short b = t[c8 * 8 + 2 * w + 1][rr];
            u[w] = (unsigned)a | ((unsigned)b << 16);
        }
        *(uint4*)(ob + (long)(c0 + rr) * R + r0 + c8 * 8) = make_uint4(u[0], u[1], u[2], u[3]);
    }
}

// ---------------- bf16 [R][C] -> bf16 [C][R] transpose, batched ----------------
__global__ void transpose_bf16(const unsigned short* __restrict__ in, unsigned short* __restrict__ out,
                               int R, int C, long inS, long outS) {
    __shared__ unsigned short t[64][66];
    const unsigned short* ib = in + (long)blockIdx.z * inS;
    unsigned short* ob = out + (long)blockIdx.z * outS;
    const int tid = threadIdx.x;
    const int r0 = blockIdx.y * 64, c0 = blockIdx.x * 64;
#pragma unroll
    for (int it = 0; it < 2; ++it) {
        int flat = it * 256 + tid;
        int r = flat >> 3, c8 = flat & 7;
        uint4 v = *(const uint4*)(ib + (long)(r0 + r) * C + c0 + c8 * 8);
        unsigned u[4] = {v.x, v.y, v.z, v.w};
#pragma unroll
        for (int w = 0; w < 4; ++w) {
            t[r][c8 * 8 + 2 * w]     = (unsigned short)(u[w] & 0xffff);
            t[r][c8 * 8 + 2 * w + 1] = (unsigned short)(u[w] >> 16);
        }
    }
    __syncthreads();
#pragma unroll
    for (int it = 0; it < 2; ++it) {
        int flat = it * 256 + tid;
        int rr = flat >> 3, c8 = flat & 7;
        unsigned u[4];
#pragma unroll
        for (int w = 0; w < 4; ++w)
            u[w] = (unsigned)t[c8 * 8 + 2 * w][rr] | ((unsigned)t[c8 * 8 + 2 * w + 1][rr] << 16);
        *(uint4*)(ob + (long)(c0 + rr) * R + r0 + c8 * 8) = make_uint4(u[0], u[1], u[2], u[3]);
    }
}

// ============== 8-phase double-buffered GEMM (proven; used for proj + final) ==============
template<int R_>
__device__ __forceinline__ void stage2(const unsigned short* __restrict__ src, int kfull,
                                       short* ldsbase, int i, int tid, int wid) {
#pragma unroll
    for (int s = 0; s < 2; ++s) {
        const int ii = i + s;
        const int r = ii * 64 + (tid >> 3);
        const int d = (tid & 7) * 16;                  // dest byte within 128B row
        const int sc = (d ^ ((r & 7) << 4)) >> 1;      // inverse-swizzled src col (elems)
        gload_lds16(src + (long)r * kfull + sc, ldsbase + ii * 4096 + wid * 512);
    }
}

// MODE 1: projections -> head-split bf16 [h][t][e]: batch0=V(x), 1=K(x), 2=Q(y)
// MODE 3: f32 split-K partial over K-slice batch
template<int BM, int BN, int KTILES, int MODE>
__global__ __launch_bounds__(512, 2)
void gemm8p(const unsigned short* __restrict__ A, const unsigned short* __restrict__ A2,
            const unsigned short* __restrict__ B, void* __restrict__ Cout,
            int kfull, float alpha, long As, long Bs, long Cs, int ldc)
{
    static_assert(KTILES >= 3, "pipeline needs >=3 K-tiles");
    constexpr int ATILE = BM * 64;
    constexpr int BTILE = BN * 64;
    constexpr int LA = BM / 64;
    constexpr int LB = BN / 64;
    constexpr int MF = BM / 32;
    constexpr int NF = BN / 64;
    constexpr int MFP = MF / 4;

    __shared__ __align__(16) short lds[2 * (ATILE + BTILE)];

    const int tid = threadIdx.x;
    const int wid = tid >> 6, lane = tid & 63;
    const int wm = wid >> 2, wn = wid & 3;
    const int fr = lane & 15, fq = lane >> 4;

    // T1: XCD chunk swizzle
    const int nwg = gridDim.x * gridDim.y * gridDim.z;
    int flat = blockIdx.x + gridDim.x * (blockIdx.y + gridDim.y * blockIdx.z);
    flat = (flat & 7) * (nwg >> 3) + (flat >> 3);
    const int bx = flat % gridDim.x;
    const int rem = flat / gridDim.x;
    const int by = rem % gridDim.y;
    const long batch = rem / gridDim.y;

    const int bm = by * BM, bn = bx * BN;

    const unsigned short* Ab;
    const unsigned short* Bb;
    int koff = 0;
    if constexpr (MODE == 1) { Ab = (batch == 2) ? A2 : A; Bb = B + batch * Bs; }
    else { Ab = A; Bb = B; koff = (int)batch * (KTILES * 64); }

    const unsigned short* Ag = Ab + (long)bm * kfull + koff;
    const unsigned short* Bg = Bb + (long)bn * kfull + koff;

    f32x4 acc[MF][NF];
#pragma unroll
    for (int i = 0; i < MF; i++)
#pragma unroll
        for (int j = 0; j < NF; j++) acc[i][j] = 0.f;

#pragma unroll
    for (int i = 0; i < LA; i += 2) stage2<BM>(Ag, kfull, lds, i, tid, wid);
#pragma unroll
    for (int i = 0; i < LB; i += 2) stage2<BN>(Bg, kfull, lds + 2 * ATILE, i, tid, wid);
#pragma unroll
    for (int i = 0; i < LB; i += 2) stage2<BN>(Bg + 64, kfull, lds + 2 * ATILE + BTILE, i, tid, wid);
    if constexpr (LB == 4) asm volatile("s_waitcnt vmcnt(4)" ::: "memory");
    else                   asm volatile("s_waitcnt vmcnt(2)" ::: "memory");
    wg_barrier();

#pragma unroll 2
    for (int t = 0; t < KTILES; ++t) {
        short* la  = lds + (t & 1) * ATILE;
        short* laN = lds + ((t + 1) & 1) * ATILE;
        short* lb  = lds + 2 * ATILE + (t & 1) * BTILE;
        const int kA = (t + 1) * 64;
        const int kB = (t + 2) * 64;

        short8 bfrag[NF][2];
#pragma unroll
        for (int q = 0; q < 4; ++q) {
            if (q == 0) {
#pragma unroll
                for (int nf = 0; nf < NF; ++nf)
#pragma unroll
                    for (int kk = 0; kk < 2; ++kk) {
                        const int r = wn * (BN / 4) + nf * 16 + fr;
                        const int cb = kk * 64 + fq * 16;
                        bfrag[nf][kk] = *(const short8*)(lb + r * 64 + ((cb ^ ((r & 7) << 4)) >> 1));
                    }
            }
            short8 afrag[MFP][2];
#pragma unroll
            for (int mf = 0; mf < MFP; ++mf)
#pragma unroll
                for (int kk = 0; kk < 2; ++kk) {
                    const int r = wm * (BM / 2) + q * (BM / 8) + mf * 16 + fr;
                    const int cb = kk * 64 + fq * 16;
                    afrag[mf][kk] = *(const short8*)(la + r * 64 + ((cb ^ ((r & 7) << 4)) >> 1));
                }
            if (t + 1 < KTILES) {
                if (q == 0) stage2<BM>(Ag + kA, kfull, laN, 0, tid, wid);
                if (q == 1 && LA == 4) stage2<BM>(Ag + kA, kfull, laN, 2, tid, wid);
            }
            if (t + 2 < KTILES) {
                if (q == 2) stage2<BN>(Bg + kB, kfull, lb, 0, tid, wid);
                if (q == 3 && LB == 4) stage2<BN>(Bg + kB, kfull, lb, 2, tid, wid);
            }
            wg_barrier();
            __builtin_amdgcn_s_setprio(1);
#pragma unroll
            for (int mf = 0; mf < MFP; ++mf)
#pragma unroll
                for (int nf = 0; nf < NF; ++nf)
#pragma unroll
                    for (int kk = 0; kk < 2; ++kk)
                        acc[q * MFP + mf][nf] = __builtin_amdgcn_mfma_f32_16x16x32_bf16(
                            afrag[mf][kk], bfrag[nf][kk], acc[q * MFP + mf][nf], 0, 0, 0);
            __builtin_amdgcn_s_setprio(0);
            if (q == 3) {
                if (t + 2 < KTILES) {
                    if constexpr (LB == 4) asm volatile("s_waitcnt vmcnt(4)" ::: "memory");
                    else                   asm volatile("s_waitcnt vmcnt(2)" ::: "memory");
                } else {
                    asm volatile("s_waitcnt vmcnt(0)" ::: "memory");
                }
            }
            wg_barrier();
        }
    }

#pragma unroll
    for (int m = 0; m < MF; ++m)
#pragma unroll
        for (int j = 0; j < 4; ++j) {
            const int row = bm + wm * (BM / 2) + m * 16 + fq * 4 + j;
#pragma unroll
            for (int n = 0; n < NF; ++n) {
                const int col = bn + wn * (BN / 4) + n * 16 + fr;
                const float v = acc[m][n][j] * alpha;
                if constexpr (MODE == 1) {
                    unsigned short* C = (unsigned short*)Cout + batch * Cs;
                    C[(long)(col >> 9) * ((long)T_SEQ * EMB) + (long)row * EMB + (col & 511)] = f2b(v);
                } else {
                    float* C = (float*)Cout + batch * ((long)T_SEQ * EMB);
                    C[(long)row * ldc + col] = v;
                }
            }
        }
}

// ============== fused attention: O = (exp(s*QK^T) @ V) / rowsum ==============
// Software-pipelined single-compute-phase schedule (r12). Block = 64 q x 1 head;
// 8 waves; grid (32 qb, 8 h), head-per-XCD swizzle. KVBLK=32, 64 iters.
// LDS (139776 B, same as r11): K dbuf [32kv][512e] @0,@32768 (swz (kv&7)<<4);
//   VT dbuf [512d][32kv] @65536,@98304 (64B rows, swz (d&3)<<4);
//   St dbuf [64q][32kv] bf16 @131072,@135168 (64B rows, swz ((row>>2)&3)<<4);
//   rs[2][64] f32 @139264.
// Iter t: B1[vmcnt(4)+lgkm(0)] ; issue stageK(t+1)->K[(t+1)&1] ;
//   compute{ QK(t) from K[t&1] || PV(t-1) from St[(t-1)&1]+VT[(t-1)&1]
//            || exp+rowsum -> St[t&1] } ; B2 ; issue stageV(t+1)->VT[(t+1)&1].
// Hazards: K[(t+1)&1] last read by QK(t-1) (before B2(t-1)<B1(t)) -- safe.
//   VT[(t+1)&1] last read by PV(t-1) this phase -- stageV issued AFTER B2. safe.
//   St[t&1] last read by PV(t-2) in phase t-1 -- safe. St visibility via lgkm+B1.
// vmcnt: queue at B1(t) = [V(t), K(t+1), V(t+1)]-ish; constant vmcnt(4) leaves
//   only newest V in flight (counted, never 0 mid-loop). Staging always issued
//   one full phase before use -> latency fully hidden.
__global__ __launch_bounds__(512, 1)
void attn_fused(const unsigned short* __restrict__ Qg, const unsigned short* __restrict__ Kg,
                const unsigned short* __restrict__ VTg, unsigned short* __restrict__ Og,
                float scale)
{
    __shared__ __align__(16) short lds[69888];   // 139776 B
    char* L = (char*)lds;
    float* rs = (float*)(L + 139264);            // [2][64]

    const int tid = threadIdx.x;
    const int wid = tid >> 6, lane = tid & 63;
    const int fr = lane & 15, fq = lane >> 4;
    const int rg = wid >> 1, ch = wid & 1;

    // head-per-XCD: orig%8 = XCD (round-robin dispatch) -> head = f>>5
    const int orig = blockIdx.x + 32 * blockIdx.y;
    const int f = (orig & 7) * 32 + (orig >> 3);
    const int qb = f & 31, h = f >> 5;
    const long TE = (long)T_SEQ * EMB;
    const unsigned short* Qh = Qg + (long)h * TE + (long)(qb * 64) * EMB;
    const unsigned short* Kh = Kg + (long)h * TE;
    const unsigned short* Vh = VTg + (long)h * TE;

    // Q fragments in registers: rows rg*16+fr, k = ks*32 + fq*8  (64 VGPR)
    short8 qreg[16];
#pragma unroll
    for (int ks = 0; ks < 16; ++ks)
        qreg[ks] = *(const short8*)(Qh + (long)(rg * 16 + fr) * EMB + ks * 32 + fq * 8);

    // ---- staging (linear LDS dest, inverse-swizzled global source) ----
    auto stK = [&](int kb, int buf) {     // [32kv][512e] = 32KB, 4 gloads/thread
#pragma unroll
        for (int it = 0; it < 4; ++it) {
            const int c = it * 512 + tid;
            const int kv = c >> 6, s = c & 63;
            gload_lds16(Kh + (long)(kb * 32 + kv) * EMB + (((s * 16) ^ ((kv & 7) << 4)) >> 1),
                        L + buf + (it * 512 + wid * 64) * 16);
        }
    };
    auto stV = [&](int kb, int buf) {     // [512d][32kv] = 32KB, 4 gloads/thread
#pragma unroll
        for (int it = 0; it < 4; ++it) {
            const int c = it * 512 + tid;
            const int d = c >> 2, s = c & 3;
            gload_lds16(Vh + (long)d * T_SEQ + kb * 32 + (((s * 16) ^ ((d & 3) << 4)) >> 1),
                        L + buf + (it * 512 + wid * 64) * 16);
        }
    };

    f32x4 oacc[4][4];
#pragma unroll
    for (int m = 0; m < 4; ++m)
#pragma unroll
        for (int n = 0; n < 4; ++n) oacc[m][n] = 0.f;
    float rsum[4] = {0.f, 0.f, 0.f, 0.f};

    const int kv = ch * 16 + fr;                 // this wave's QK kv column
    const int swA = ((fr >> 2) & 3) << 4;        // St-read swz for sa (row=m*16+fr)

    // prologue: K(0), V(0)
    stK(0, 0);
    stV(0, 65536);

#pragma unroll 1
    for (int t = 0; t < 64; ++t) {
        asm volatile("s_waitcnt vmcnt(4) lgkmcnt(0)" ::: "memory");
        wg_barrier();                                      // B1
        if (t + 1 < 64) stK(t + 1, ((t + 1) & 1) ? 32768 : 0);

        const char* Kb_ = L + ((t & 1) ? 32768 : 0);
        const char* Sp_ = L + 131072 + ((t & 1) ? 4096 : 0);       // St[t&1] (write)
        const char* Sr_ = L + 131072 + (((t - 1) & 1) ? 4096 : 0); // St[(t-1)&1] (read)
        const char* Vr_ = L + 65536 + (((t - 1) & 1) ? 32768 : 0); // VT[(t-1)&1] (read)

        // ---- QK(t): 16 ks, 2 k-split accs ----
        f32x4 sacc0 = 0.f, sacc1 = 0.f;
#pragma unroll
        for (int ks = 0; ks < 16; ++ks) {
            const short8 bfr = *(const short8*)(Kb_ + kv * 1024 +
                                ((ks * 64 + fq * 16) ^ ((kv & 7) << 4)));
            if (ks & 1) sacc1 = __builtin_amdgcn_mfma_f32_16x16x32_bf16(qreg[ks], bfr, sacc1, 0, 0, 0);
            else        sacc0 = __builtin_amdgcn_mfma_f32_16x16x32_bf16(qreg[ks], bfr, sacc0, 0, 0, 0);
        }

        // ---- PV(t-1) ----
        if (t > 0) {
            short8 sa[4], vb[4];
#pragma unroll
            for (int m = 0; m < 4; ++m) {
                const int row = m * 16 + fr;
                sa[m] = *(const short8*)(Sr_ + row * 64 + ((fq * 16) ^ swA));
            }
#pragma unroll
            for (int n = 0; n < 4; ++n) {
                const int d = wid * 64 + n * 16 + fr;
                vb[n] = *(const short8*)(Vr_ + d * 64 + ((fq * 16) ^ ((d & 3) << 4)));
            }
            __builtin_amdgcn_s_setprio(1);
#pragma unroll
            for (int m = 0; m < 4; ++m)
#pragma unroll
                for (int n = 0; n < 4; ++n)
                    oacc[m][n] = __builtin_amdgcn_mfma_f32_16x16x32_bf16(
                        sa[m], vb[n], oacc[m][n], 0, 0, 0);
            __builtin_amdgcn_s_setprio(0);
        }

        // ---- exp + rowsum + St(t) store ----
#pragma unroll
        for (int j = 0; j < 4; ++j) {
            const float v = __expf(scale * (sacc0[j] + sacc1[j]));
            rsum[j] += v;
            const int row = rg * 16 + fq * 4 + j;
            *(unsigned short*)((char*)Sp_ + row * 64 +
                ((kv * 2) ^ (((row >> 2) & 3) << 4))) = f2b(v);
        }

        wg_barrier();                                      // B2
        if (t + 1 < 64) stV(t + 1, 65536 + (((t + 1) & 1) ? 32768 : 0));
    }

    // ---- epilogue: PV(63) ----
    asm volatile("s_waitcnt vmcnt(0) lgkmcnt(0)" ::: "memory");
    wg_barrier();
    {
        const char* Sr_ = L + 131072 + 4096;    // St[63&1] = St[1]
        const char* Vr_ = L + 65536 + 32768;    // VT[63&1] = VT[1]
        short8 sa[4], vb[4];
#pragma unroll
        for (int m = 0; m < 4; ++m) {
            const int row = m * 16 + fr;
            sa[m] = *(const short8*)(Sr_ + row * 64 + ((fq * 16) ^ swA));
        }
#pragma unroll
        for (int n = 0; n < 4; ++n) {
            const int d = wid * 64 + n * 16 + fr;
            vb[n] = *(const short8*)(Vr_ + d * 64 + ((fq * 16) ^ ((d & 3) << 4)));
        }
#pragma unroll
        for (int m = 0; m < 4; ++m)
#pragma unroll
            for (int n = 0; n < 4; ++n)
                oacc[m][n] = __builtin_amdgcn_mfma_f32_16x16x32_bf16(
                    sa[m], vb[n], oacc[m][n], 0, 0, 0);
    }

    // ---- rowsum reduce -> rs, then normalize + write O ----
#pragma unroll
    for (int j = 0; j < 4; ++j) {
        float v = rsum[j];
        v += __shfl_xor(v, 1);
        v += __shfl_xor(v, 2);
        v += __shfl_xor(v, 4);
        v += __shfl_xor(v, 8);
        if (fr == 0) rs[ch * 64 + rg * 16 + fq * 4 + j] = v;
    }
    asm volatile("s_waitcnt lgkmcnt(0)" ::: "memory");
    wg_barrier();

#pragma unroll
    for (int m = 0; m < 4; ++m)
#pragma unroll
        for (int j = 0; j < 4; ++j) {
            const int row = m * 16 + fq * 4 + j;
            const float rinv = 1.0f / (rs[row] + rs[64 + row]);
#pragma unroll
            for (int n = 0; n < 4; ++n) {
                const int d = wid * 64 + n * 16 + fr;
                Og[(long)(qb * 64 + row) * HEAD_ALL + h * EMB + d] = f2b(oacc[m][n][j] * rinv);
            }
        }
}

// ---------------- split-K reduce + bias: out = sum_s part[s] + bias ----------------
__global__ void reduce_bias(const float* __restrict__ part, const float* __restrict__ bias,
                            float* __restrict__ out) {
    const int i = blockIdx.x * 256 + threadIdx.x;
    const long stride4 = (long)T_SEQ * EMB / 4;
    const f32x4* p = (const f32x4*)part;
    f32x4 s = p[i];
#pragma unroll
    for (int sl = 1; sl < 8; ++sl) s += p[i + sl * stride4];
    f32x4 b = *(const f32x4*)(bias + ((i * 4) % EMB));
    *((f32x4*)out + i) = s + b;
}

extern "C" void kernel_launch(void* const* d_in, const int* in_sizes, int n_in,
                              void* d_out, int out_size, void* d_ws, size_t ws_size,
                              hipStream_t stream)
{
    const float* x  = (const float*)d_in[0];
    const float* y  = (const float*)d_in[1];
    const float* Wk = (const float*)d_in[2];
    const float* Wq = (const float*)d_in[3];
    const float* Wv = (const float*)d_in[4];
    const float* Wu = (const float*)d_in[5];
    const float* bu = (const float*)d_in[6];
    char* ws = (char*)d_ws;
    const size_t MB = 1024ull * 1024ull;

    // Workspace layout (r7 offsets kept)
    unsigned short* xb   = (unsigned short*)(ws + 0);        // 2 MB  [transient]
    unsigned short* yb   = (unsigned short*)(ws + 2 * MB);   // 2 MB  [transient]
    unsigned short* WT3  = (unsigned short*)(ws + 4 * MB);   // 12 MB: WvT,WkT,WqT [transient]
    unsigned short* PRJ  = (unsigned short*)(ws + 48 * MB);  // Vb@48 [transient], Kb@64, Qb@80
    unsigned short* Vb   = (unsigned short*)(ws + 48 * MB);
    unsigned short* Kb   = (unsigned short*)(ws + 64 * MB);
    unsigned short* Qb   = (unsigned short*)(ws + 80 * MB);
    unsigned short* WuT  = (unsigned short*)(ws + 96 * MB);  // 4 MB
    unsigned short* VTb  = (unsigned short*)(ws + 100 * MB); // 16 MB
    unsigned short* Ob   = (unsigned short*)(ws + 116 * MB); // 16 MB
    float*          part = (float*)(ws + 0);                 // 32 MB f32

    const float scale2 = 0.04419417382415922f;  // 512^-0.5
    const long TE = (long)T_SEQ * EMB;

    // 1) converts
    cvt_bf16_2<<<dim3(512, 2), dim3(256), 0, stream>>>(x, y, xb, yb, T_SEQ * EMB / 8);
    transpose_cvt3_f32<<<dim3(HEAD_ALL / 64, EMB / 64, 3), dim3(256), 0, stream>>>(
        Wv, Wk, Wq, WT3, EMB, HEAD_ALL, (long)2 * MB);
    transpose_cvt3_f32<<<dim3(EMB / 64, HEAD_ALL / 64, 1), dim3(256), 0, stream>>>(
        Wu, nullptr, nullptr, WuT, HEAD_ALL, EMB, 0);

    // 2) fused projections -> [3][h][t][e] bf16 at PRJ (batch0=V(x), 1=K(x), 2=Q(y))
    gemm8p<256, 256, 8, 1><<<dim3(HEAD_ALL / 256, T_SEQ / 256, 3), 512, 0, stream>>>(
        xb, yb, WT3, PRJ, EMB, 1.f, 0, (long)2 * MB, (long)8 * MB, 0);

    // 3) V -> V^T per head
    transpose_bf16<<<dim3(EMB / 64, T_SEQ / 64, NH), dim3(256), 0, stream>>>(
        Vb, VTb, T_SEQ, EMB, TE, TE);

    // 4) fused attention: O = softmax(QK^T * s) @ V  (no-max softmax, pipelined)
    attn_fused<<<dim3(32, 8), 512, 0, stream>>>(Qb, Kb, VTb, Ob, scale2);

    // 5) split-K=8 final GEMM: part[s] = O @ Wu over K-slice s (K=512 each)
    gemm8p<256, 128, 8, 3><<<dim3(EMB / 128, T_SEQ / 256, 8), 512, 0, stream>>>(
        Ob, nullptr, WuT, part, HEAD_ALL, 1.f, 0, 0, 0, EMB);

    // 6) out = sum(part) + bias, f32
    reduce_bias<<<dim3(T_SEQ * EMB / 4 / 256), dim3(256), 0, stream>>>(part, bu, (float*)d_out);
}

// Round 13
// 173.588 us; speedup vs baseline: 1.1409x; 1.1409x over previous
//
#include <hip/hip_runtime.h>
#include <hip/hip_bf16.h>
#include <stdint.h>

#define T_SEQ 2048
#define EMB   512
#define NH    8
#define HEAD_ALL 4096   // NH*EMB

typedef __attribute__((ext_vector_type(8))) short short8;
typedef __attribute__((ext_vector_type(4))) float f32x4;

__device__ __forceinline__ unsigned short f2b(float f) {
    __hip_bfloat16 h = __float2bfloat16(f);
    return *reinterpret_cast<unsigned short*>(&h);
}
__device__ __forceinline__ float b2f(unsigned short u) {
    return __uint_as_float(((unsigned)u) << 16);
}
__device__ __forceinline__ void gload_lds16(const void* g, void* l) {
    __builtin_amdgcn_global_load_lds((__attribute__((address_space(1))) void*)(void*)(g),
                                     (__attribute__((address_space(3))) void*)(l), 16, 0, 0);
}
__device__ __forceinline__ void wg_barrier() {
    asm volatile("" ::: "memory");
    __builtin_amdgcn_s_barrier();
    asm volatile("" ::: "memory");
}

// ---------------- f32 -> bf16 convert, two tensors in one launch ----------------
__global__ void cvt_bf16_2(const float* __restrict__ a, const float* __restrict__ b,
                           unsigned short* __restrict__ oa, unsigned short* __restrict__ ob, int n8) {
    const float* in = blockIdx.y ? b : a;
    unsigned short* out = blockIdx.y ? ob : oa;
    int i = blockIdx.x * 256 + threadIdx.x;
    if (i >= n8) return;
    const f32x4* p = (const f32x4*)in + 2 * (size_t)i;
    f32x4 va = p[0], vb = p[1];
    uint4 o;
    o.x = (unsigned)f2b(va[0]) | ((unsigned)f2b(va[1]) << 16);
    o.y = (unsigned)f2b(va[2]) | ((unsigned)f2b(va[3]) << 16);
    o.z = (unsigned)f2b(vb[0]) | ((unsigned)f2b(vb[1]) << 16);
    o.w = (unsigned)f2b(vb[2]) | ((unsigned)f2b(vb[3]) << 16);
    *((uint4*)out + i) = o;
}

// ------- f32 [R][C] -> bf16 [C][R] transpose-convert, 4 weights in one launch -------
// z<3: Wv/Wk/Wq (R=EMB, C=HEAD_ALL, grid x=64,y=8) -> o012 + z*2M elems
// z=3: Wu (R=HEAD_ALL, C=EMB, 8x64 geometry remapped from the flat 64x8 index) -> o3
__global__ void transpose_cvt4_f32(const float* __restrict__ w0, const float* __restrict__ w1,
                                   const float* __restrict__ w2, const float* __restrict__ w3,
                                   unsigned short* __restrict__ o012, unsigned short* __restrict__ o3) {
    __shared__ unsigned short t[64][66];
    const int z = blockIdx.z;
    const float* in;
    unsigned short* ob;
    int R, C, bx, by;
    if (z < 3) {
        in = (z == 0) ? w0 : ((z == 1) ? w1 : w2);
        ob = o012 + (long)z * 2 * 1024 * 1024;
        R = EMB; C = HEAD_ALL; bx = blockIdx.x; by = blockIdx.y;
    } else {
        in = w3; ob = o3;
        R = HEAD_ALL; C = EMB;
        const int flat = blockIdx.x + blockIdx.y * 64;   // 0..511
        bx = flat & 7; by = flat >> 3;                   // 8 x 64
    }
    const int tid = threadIdx.x;
    const int r0 = by * 64, c0 = bx * 64;
#pragma unroll
    for (int it = 0; it < 4; ++it) {
        int flat = it * 256 + tid;
        int r = flat >> 4, c4 = flat & 15;
        f32x4 v = *(const f32x4*)(in + (long)(r0 + r) * C + c0 + c4 * 4);
#pragma unroll
        for (int w = 0; w < 4; ++w) t[r][c4 * 4 + w] = f2b(v[w]);
    }
    __syncthreads();
#pragma unroll
    for (int it = 0; it < 2; ++it) {
        int flat = it * 256 + tid;
        int rr = flat >> 3, c8 = flat & 7;
        unsigned u[4];
#pragma unroll
        for (int w = 0; w < 4; ++w) {
            unsigned short a = t[c8 * 8 + 2 * w][rr];
            unsigned short b = t[c8 * 8 + 2 * w + 1][rr];
            u[w] = (unsigned)a | ((unsigned)b << 16);
        }
        *(uint4*)(ob + (long)(c0 + rr) * R + r0 + c8 * 8) = make_uint4(u[0], u[1], u[2], u[3]);
    }
}

// ---------------- bf16 [R][C] -> bf16 [C][R] transpose, batched ----------------
__global__ void transpose_bf16(const unsigned short* __restrict__ in, unsigned short* __restrict__ out,
                               int R, int C, long inS, long outS) {
    __shared__ unsigned short t[64][66];
    const unsigned short* ib = in + (long)blockIdx.z * inS;
    unsigned short* ob = out + (long)blockIdx.z * outS;
    const int tid = threadIdx.x;
    const int r0 = blockIdx.y * 64, c0 = blockIdx.x * 64;
#pragma unroll
    for (int it = 0; it < 2; ++it) {
        int flat = it * 256 + tid;
        int r = flat >> 3, c8 = flat & 7;
        uint4 v = *(const uint4*)(ib + (long)(r0 + r) * C + c0 + c8 * 8);
        unsigned u[4] = {v.x, v.y, v.z, v.w};
#pragma unroll
        for (int w = 0; w < 4; ++w) {
            t[r][c8 * 8 + 2 * w]     = (unsigned short)(u[w] & 0xffff);
            t[r][c8 * 8 + 2 * w + 1] = (unsigned short)(u[w] >> 16);
        }
    }
    __syncthreads();
#pragma unroll
    for (int it = 0; it < 2; ++it) {
        int flat = it * 256 + tid;
        int rr = flat >> 3, c8 = flat & 7;
        unsigned u[4];
#pragma unroll
        for (int w = 0; w < 4; ++w)
            u[w] = (unsigned)t[c8 * 8 + 2 * w][rr] | ((unsigned)t[c8 * 8 + 2 * w + 1][rr] << 16);
        *(uint4*)(ob + (long)(c0 + rr) * R + r0 + c8 * 8) = make_uint4(u[0], u[1], u[2], u[3]);
    }
}

// ============== 8-phase double-buffered GEMM: C = op(alpha * A @ B'^T) ==============
// A: M x kfull row-major bf16; B': N x kfull row-major bf16 (B transposed).
// BMxBN tile, BK=64, 512 threads = 8 waves (2M x 4N), 16x16x32 bf16 MFMA.
// T2: linear LDS dest for global_load_lds; inverse-XOR-swizzled GLOBAL source
// (byte ^ ((row&7)<<4)) + same XOR on ds_read. T1: XCD chunk swizzle (nwg%8==0).
// Pipeline: A_{t+1} staged q0(/q1), B_{t+2} q2(/q3); vmcnt(LB) counted at q3.
// MODE 1: projections -> head-split bf16 [h][t][e]: batch0=V(x), 1=K(x), 2=Q(y)
// MODE 2: S~ = exp(alpha*acc) bf16 + per-(bx,wn) row partial sums -> rpart
// MODE 3: f32 split-K partial over K-slice batch
// MODE 4: PV: bf16 out * rinv[row] (row sums combined from rpart in prologue)
template<int R_>
__device__ __forceinline__ void stage2(const unsigned short* __restrict__ src, int kfull,
                                       short* ldsbase, int i, int tid, int wid) {
#pragma unroll
    for (int s = 0; s < 2; ++s) {
        const int ii = i + s;
        const int r = ii * 64 + (tid >> 3);
        const int d = (tid & 7) * 16;                  // dest byte within 128B row
        const int sc = (d ^ ((r & 7) << 4)) >> 1;      // inverse-swizzled src col (elems)
        gload_lds16(src + (long)r * kfull + sc, ldsbase + ii * 4096 + wid * 512);
    }
}

template<int BM, int BN, int KTILES, int MODE>
__global__ __launch_bounds__(512, 2)
void gemm8p(const unsigned short* __restrict__ A, const unsigned short* __restrict__ A2,
            const unsigned short* __restrict__ B, void* __restrict__ Cout,
            float* __restrict__ rpart,
            int kfull, float alpha, long As, long Bs, long Cs, int ldc)
{
    static_assert(KTILES >= 3, "pipeline needs >=3 K-tiles");
    constexpr int ATILE = BM * 64;
    constexpr int BTILE = BN * 64;
    constexpr int LA = BM / 64;
    constexpr int LB = BN / 64;
    constexpr int MF = BM / 32;           // M-frags per wave
    constexpr int NF = BN / 64;           // N-frags per wave
    constexpr int MFP = MF / 4;           // M-frags per phase
    constexpr int LDSN = 2 * (ATILE + BTILE);

    __shared__ __align__(16) short lds[LDSN + ((MODE == 4) ? 2 * BM : 0)];

    const int tid = threadIdx.x;
    const int wid = tid >> 6, lane = tid & 63;
    const int wm = wid >> 2, wn = wid & 3;
    const int fr = lane & 15, fq = lane >> 4;

    // ---- T1: XCD chunk swizzle ----
    const int nwg = gridDim.x * gridDim.y * gridDim.z;
    int flat = blockIdx.x + gridDim.x * (blockIdx.y + gridDim.y * blockIdx.z);
    flat = (flat & 7) * (nwg >> 3) + (flat >> 3);
    const int bx = flat % gridDim.x;
    const int rem = flat / gridDim.x;
    const int by = rem % gridDim.y;
    const long batch = rem / gridDim.y;

    const int bm = by * BM, bn = bx * BN;

    const unsigned short* Ab;
    const unsigned short* Bb;
    int koff = 0;
    if constexpr (MODE == 1) { Ab = (batch == 2) ? A2 : A; Bb = B + batch * Bs; }
    else if constexpr (MODE == 3) { Ab = A; Bb = B; koff = (int)batch * (KTILES * 64); }
    else { Ab = A + batch * As; Bb = B + batch * Bs; }

    const unsigned short* Ag = Ab + (long)bm * kfull + koff;
    const unsigned short* Bg = Bb + (long)bn * kfull + koff;

    f32x4 acc[MF][NF];
#pragma unroll
    for (int i = 0; i < MF; i++)
#pragma unroll
        for (int j = 0; j < NF; j++) acc[i][j] = 0.f;

    // ---- MODE 4: combine row partial sums -> rinv in LDS ----
    float* rinv = (float*)(lds + LDSN);
    if constexpr (MODE == 4) {
        for (int r = tid; r < BM; r += 512) {
            float s = 0.f;
#pragma unroll
            for (int i = 0; i < 32; ++i) s += rpart[((long)batch * 32 + i) * T_SEQ + bm + r];
            rinv[r] = 1.0f / s;
        }
        asm volatile("s_waitcnt lgkmcnt(0)" ::: "memory");
    }

    // ---- prologue: stage A_0, B_0, B_1 ----
#pragma unroll
    for (int i = 0; i < LA; i += 2) stage2<BM>(Ag, kfull, lds, i, tid, wid);
#pragma unroll
    for (int i = 0; i < LB; i += 2) stage2<BN>(Bg, kfull, lds + 2 * ATILE, i, tid, wid);
#pragma unroll
    for (int i = 0; i < LB; i += 2) stage2<BN>(Bg + 64, kfull, lds + 2 * ATILE + BTILE, i, tid, wid);
    if constexpr (LB == 4) asm volatile("s_waitcnt vmcnt(4)" ::: "memory");
    else                   asm volatile("s_waitcnt vmcnt(2)" ::: "memory");
    wg_barrier();

    // ---- main loop ----
#pragma unroll 2
    for (int t = 0; t < KTILES; ++t) {
        short* la  = lds + (t & 1) * ATILE;
        short* laN = lds + ((t + 1) & 1) * ATILE;
        short* lb  = lds + 2 * ATILE + (t & 1) * BTILE;
        const int kA = (t + 1) * 64;
        const int kB = (t + 2) * 64;

        short8 bfrag[NF][2];
#pragma unroll
        for (int q = 0; q < 4; ++q) {
            if (q == 0) {
#pragma unroll
                for (int nf = 0; nf < NF; ++nf)
#pragma unroll
                    for (int kk = 0; kk < 2; ++kk) {
                        const int r = wn * (BN / 4) + nf * 16 + fr;
                        const int cb = kk * 64 + fq * 16;
                        bfrag[nf][kk] = *(const short8*)(lb + r * 64 + ((cb ^ ((r & 7) << 4)) >> 1));
                    }
            }
            short8 afrag[MFP][2];
#pragma unroll
            for (int mf = 0; mf < MFP; ++mf)
#pragma unroll
                for (int kk = 0; kk < 2; ++kk) {
                    const int r = wm * (BM / 2) + q * (BM / 8) + mf * 16 + fr;
                    const int cb = kk * 64 + fq * 16;
                    afrag[mf][kk] = *(const short8*)(la + r * 64 + ((cb ^ ((r & 7) << 4)) >> 1));
                }
            if (t + 1 < KTILES) {
                if (q == 0) stage2<BM>(Ag + kA, kfull, laN, 0, tid, wid);
                if (q == 1 && LA == 4) stage2<BM>(Ag + kA, kfull, laN, 2, tid, wid);
            }
            if (t + 2 < KTILES) {
                if (q == 2) stage2<BN>(Bg + kB, kfull, lb, 0, tid, wid);
                if (q == 3 && LB == 4) stage2<BN>(Bg + kB, kfull, lb, 2, tid, wid);
            }
            wg_barrier();
            __builtin_amdgcn_s_setprio(1);
#pragma unroll
            for (int mf = 0; mf < MFP; ++mf)
#pragma unroll
                for (int nf = 0; nf < NF; ++nf)
#pragma unroll
                    for (int kk = 0; kk < 2; ++kk)
                        acc[q * MFP + mf][nf] = __builtin_amdgcn_mfma_f32_16x16x32_bf16(
                            afrag[mf][kk], bfrag[nf][kk], acc[q * MFP + mf][nf], 0, 0, 0);
            __builtin_amdgcn_s_setprio(0);
            if (q == 3) {
                if (t + 2 < KTILES) {
                    if constexpr (LB == 4) asm volatile("s_waitcnt vmcnt(4)" ::: "memory");
                    else                   asm volatile("s_waitcnt vmcnt(2)" ::: "memory");
                } else {
                    asm volatile("s_waitcnt vmcnt(0)" ::: "memory");
                }
            }
            wg_barrier();
        }
    }

    // ---- epilogue ----
#pragma unroll
    for (int m = 0; m < MF; ++m)
#pragma unroll
        for (int j = 0; j < 4; ++j) {
            const int row = bm + wm * (BM / 2) + m * 16 + fq * 4 + j;
            float rowsum = 0.f;
#pragma unroll
            for (int n = 0; n < NF; ++n) {
                const int col = bn + wn * (BN / 4) + n * 16 + fr;
                const float v = acc[m][n][j] * alpha;
                if constexpr (MODE == 1) {
                    unsigned short* C = (unsigned short*)Cout + batch * Cs;
                    C[(long)(col >> 9) * ((long)T_SEQ * EMB) + (long)row * EMB + (col & 511)] = f2b(v);
                } else if constexpr (MODE == 2) {
                    unsigned short* C = (unsigned short*)Cout + batch * Cs;
                    const unsigned short us = f2b(__expf(v));
                    C[(long)row * ldc + col] = us;
                    rowsum += b2f(us);           // sum the ROUNDED value (consistency)
                } else if constexpr (MODE == 3) {
                    float* C = (float*)Cout + batch * ((long)T_SEQ * EMB);
                    C[(long)row * ldc + col] = v;
                } else { // MODE 4
                    unsigned short* C = (unsigned short*)Cout + batch * Cs;
                    C[(long)row * ldc + col] = f2b(v * rinv[row - bm]);
                }
            }
            if constexpr (MODE == 2) {
                rowsum += __shfl_xor(rowsum, 1);
                rowsum += __shfl_xor(rowsum, 2);
                rowsum += __shfl_xor(rowsum, 4);
                rowsum += __shfl_xor(rowsum, 8);
                if (fr == 0)
                    rpart[(((long)batch * 8 + bx) * 4 + wn) * T_SEQ + row] = rowsum;
            }
        }
}

// ---------------- split-K reduce + bias: out = sum_s part[s] + bias ----------------
__global__ void reduce_bias(const float* __restrict__ part, const float* __restrict__ bias,
                            float* __restrict__ out) {
    const int i = blockIdx.x * 256 + threadIdx.x;   // float4 index; total T*E/4
    const long stride4 = (long)T_SEQ * EMB / 4;
    const f32x4* p = (const f32x4*)part;
    f32x4 s = p[i];
#pragma unroll
    for (int sl = 1; sl < 8; ++sl) s += p[i + sl * stride4];
    f32x4 b = *(const f32x4*)(bias + ((i * 4) % EMB));
    *((f32x4*)out + i) = s + b;
}

extern "C" void kernel_launch(void* const* d_in, const int* in_sizes, int n_in,
                              void* d_out, int out_size, void* d_ws, size_t ws_size,
                              hipStream_t stream)
{
    const float* x  = (const float*)d_in[0];
    const float* y  = (const float*)d_in[1];
    const float* Wk = (const float*)d_in[2];
    const float* Wq = (const float*)d_in[3];
    const float* Wv = (const float*)d_in[4];
    const float* Wu = (const float*)d_in[5];
    const float* bu = (const float*)d_in[6];
    char* ws = (char*)d_ws;
    const size_t MB = 1024ull * 1024ull;

    // Workspace layout, 134 MB total (r7 proven layout).
    // [0,64MB) = S~ union. Transients inside it (dead before S~ is written):
    // xb@0(2), yb@2(2), WT3@4(12), Vb@48(16). Split-K partials (32MB f32)
    // also live at @0 -- written after PV consumed S~.
    unsigned short* Sb   = (unsigned short*)(ws + 0);        // 64 MB [union]
    unsigned short* xb   = (unsigned short*)(ws + 0);        // 2 MB  [transient]
    unsigned short* yb   = (unsigned short*)(ws + 2 * MB);   // 2 MB  [transient]
    unsigned short* WT3  = (unsigned short*)(ws + 4 * MB);   // 12 MB: WvT,WkT,WqT [transient]
    unsigned short* PRJ  = (unsigned short*)(ws + 48 * MB);  // Vb@48 [transient], Kb@64, Qb@80
    unsigned short* Vb   = (unsigned short*)(ws + 48 * MB);
    unsigned short* WuT  = (unsigned short*)(ws + 96 * MB);  // 4 MB
    unsigned short* VTb  = (unsigned short*)(ws + 100 * MB); // 16 MB
    unsigned short* Ob   = (unsigned short*)(ws + 116 * MB); // 16 MB
    float*          rpart= (float*)(ws + 132 * MB);          // 2 MB: [8h][8bx][4wn][2048row]
    float*          part = (float*)(ws + 0);                 // 32 MB f32 [union w/ Sb]
    unsigned short* Kb   = (unsigned short*)(ws + 64 * MB);
    unsigned short* Qb   = (unsigned short*)(ws + 80 * MB);

    const float scale2 = 0.04419417382415922f;  // 512^-0.5 == (e^-0.25)^2
    const long TE = (long)T_SEQ * EMB;          // 1048576

    // 1) converts (x,y fused; Wv,Wk,Wq,Wu transposes fused into one z=4 launch)
    cvt_bf16_2<<<dim3(512, 2), dim3(256), 0, stream>>>(x, y, xb, yb, T_SEQ * EMB / 8);
    transpose_cvt4_f32<<<dim3(HEAD_ALL / 64, EMB / 64, 4), dim3(256), 0, stream>>>(
        Wv, Wk, Wq, Wu, WT3, WuT);

    // 2) fused projections -> [3][h][t][e] bf16 at PRJ (batch0=V(x), 1=K(x), 2=Q(y))
    gemm8p<256, 256, 8, 1><<<dim3(HEAD_ALL / 256, T_SEQ / 256, 3), 512, 0, stream>>>(
        xb, yb, WT3, PRJ, nullptr, EMB, 1.f, 0, (long)2 * MB, (long)8 * MB, 0);

    // 3) V -> V^T per head (coalesced LDS-tiled transpose)
    transpose_bf16<<<dim3(EMB / 64, T_SEQ / 64, NH), dim3(256), 0, stream>>>(
        Vb, VTb, T_SEQ, EMB, TE, TE);

    // 4) S~ = exp((Q @ K^T) * e^-0.5), batched over heads; row partial sums -> rpart
    gemm8p<256, 256, 8, 2><<<dim3(T_SEQ / 256, T_SEQ / 256, NH), 512, 0, stream>>>(
        Qb, nullptr, Kb, Sb, rpart, EMB, scale2, TE, TE, (long)T_SEQ * T_SEQ, T_SEQ);

    // 5) O = (S~ @ V) / rowsum, batched; head h cols at [t][4096] offset h*512
    gemm8p<128, 256, 32, 4><<<dim3(EMB / 256, T_SEQ / 128, NH), 512, 0, stream>>>(
        Sb, nullptr, VTb, Ob, rpart, T_SEQ, 1.f, (long)T_SEQ * T_SEQ, TE, (long)EMB, HEAD_ALL);

    // 6) split-K=8 final GEMM: part[s] = O @ Wu over K-slice s (K=512 each)
    gemm8p<256, 128, 8, 3><<<dim3(EMB / 128, T_SEQ / 256, 8), 512, 0, stream>>>(
        Ob, nullptr, WuT, part, nullptr, HEAD_ALL, 1.f, 0, 0, 0, EMB);

    // 7) out = sum(part) + bias, f32
    reduce_bias<<<dim3(T_SEQ * EMB / 4 / 256), dim3(256), 0, stream>>>(part, bu, (float*)d_out);
}